// Round 1
// baseline (493.317 us; speedup 1.0000x reference)
//
#include <hip/hip_runtime.h>
#include <math.h>

#define BB 2
#define LL 4096
#define HH 8
#define DD 64
#define UU 45
#define TILE 128
#define NTILES (LL / TILE) // 32

__device__ __forceinline__ int qkv_idx(int b, int l, int h, int d) {
    return ((b * LL + l) * HH + h) * DD + d;
}

// ---------------- Kernel 1: sparsity metric M[b,h,q] = max_s(QK_s) - mean-ish ----
// One wave (64 lanes) per query. lane<UU handles sampled key s=lane; Q row is
// held one element per lane (lane=d) and broadcast via shuffles.
__global__ __launch_bounds__(256) void k_computeM(
        const float* __restrict__ Q, const float* __restrict__ K,
        const int* __restrict__ idx, float* __restrict__ M) {
    int w = (blockIdx.x * blockDim.x + threadIdx.x) >> 6; // global wave id
    int lane = threadIdx.x & 63;
    int q = w % LL;
    int bh = w / LL;            // b*HH + h
    int h = bh % HH, b = bh / HH;

    float qv = Q[qkv_idx(b, q, h, lane)]; // lane = d

    int ks = idx[q * UU + (lane < UU ? lane : 0)];
    const float4* krow = (const float4*)(K + qkv_idx(b, ks, h, 0));

    float dot = 0.f;
#pragma unroll
    for (int i = 0; i < 16; ++i) {
        float4 kk = krow[i];
        dot = fmaf(__shfl(qv, 4 * i + 0, 64), kk.x, dot);
        dot = fmaf(__shfl(qv, 4 * i + 1, 64), kk.y, dot);
        dot = fmaf(__shfl(qv, 4 * i + 2, 64), kk.z, dot);
        dot = fmaf(__shfl(qv, 4 * i + 3, 64), kk.w, dot);
    }

    float mval = (lane < UU) ? dot : -INFINITY;
    float sval = (lane < UU) ? dot : 0.f;
#pragma unroll
    for (int off = 32; off >= 1; off >>= 1) {
        mval = fmaxf(mval, __shfl_xor(mval, off, 64));
        sval += __shfl_xor(sval, off, 64);
    }
    if (lane == 0) M[bh * LL + q] = mval - sval * (1.0f / LL);
}

// ---------------- Kernel 2: top-45 indices per (b,h), lowest-index tie-break ----
__global__ __launch_bounds__(256) void k_topk(
        const float* __restrict__ M, int* __restrict__ Mtop) {
    int bh = blockIdx.x;
    __shared__ float vals[LL];
    __shared__ float rv[256];
    __shared__ int ri[256];
    int t = threadIdx.x;
    for (int i = t; i < LL; i += 256) vals[i] = M[bh * LL + i];
    __syncthreads();

    for (int iter = 0; iter < UU; ++iter) {
        float best = -INFINITY;
        int bi = LL;
        for (int i = t; i < LL; i += 256) {
            float v = vals[i];
            if (v > best || (v == best && i < bi)) { best = v; bi = i; }
        }
        rv[t] = best; ri[t] = bi;
        __syncthreads();
        for (int off = 128; off >= 1; off >>= 1) {
            if (t < off) {
                float v2 = rv[t + off]; int i2 = ri[t + off];
                if (v2 > rv[t] || (v2 == rv[t] && i2 < ri[t])) { rv[t] = v2; ri[t] = i2; }
            }
            __syncthreads();
        }
        int sel = ri[0];
        if (t == 0) {
            Mtop[bh * UU + iter] = sel;
            vals[sel] = -INFINITY;
        }
        __syncthreads();
    }
}

// ---------------- Kernel 3: per-tile sums of V over l (for cumsum) -------------
__global__ __launch_bounds__(256) void k_tilesum(
        const float* __restrict__ V, float* __restrict__ tsum) {
    int blk = blockIdx.x; // ((b*HH+h)*NTILES + tile)
    int tile = blk % NTILES;
    int bh = blk / NTILES;
    int h = bh % HH, b = bh / HH;
    int d = threadIdx.x & 63, g = threadIdx.x >> 6; // g in 0..3
    const int CH = TILE / 4;                        // 32
    int l0 = tile * TILE + g * CH;
    float acc = 0.f;
    for (int i = 0; i < CH; ++i) acc += V[qkv_idx(b, l0 + i, h, d)];
    __shared__ float red[4][DD];
    red[g][d] = acc;
    __syncthreads();
    if (g == 0) tsum[blk * DD + d] = red[0][d] + red[1][d] + red[2][d] + red[3][d];
}

// ---------------- Kernel 4: exclusive scan of tile sums (32 tiles, serial) -----
__global__ void k_scantiles(float* __restrict__ tsum) {
    int bh = blockIdx.x;
    int d = threadIdx.x; // 64 threads
    float off = 0.f;
    for (int t = 0; t < NTILES; ++t) {
        int i = (bh * NTILES + t) * DD + d;
        float v = tsum[i];
        tsum[i] = off;
        off += v;
    }
}

// ---------------- Kernel 5: write cumsum(V) to out -----------------------------
__global__ __launch_bounds__(256) void k_cumsum(
        const float* __restrict__ V, const float* __restrict__ tsum,
        float* __restrict__ out) {
    int blk = blockIdx.x;
    int tile = blk % NTILES;
    int bh = blk / NTILES;
    int h = bh % HH, b = bh / HH;
    int d = threadIdx.x & 63, g = threadIdx.x >> 6;
    const int CH = TILE / 4;
    int l0 = tile * TILE + g * CH;

    __shared__ float red[4][DD];
    float acc = 0.f;
    for (int i = 0; i < CH; ++i) acc += V[qkv_idx(b, l0 + i, h, d)];
    red[g][d] = acc;
    __syncthreads();

    float off = tsum[blk * DD + d];
    for (int gg = 0; gg < g; ++gg) off += red[gg][d];

    float run = off;
    for (int i = 0; i < CH; ++i) {
        run += V[qkv_idx(b, l0 + i, h, d)];
        out[qkv_idx(b, l0 + i, h, d)] = run;
    }
}

// ---------------- Kernel 6: full attention rows for selected queries, scatter --
__global__ __launch_bounds__(256) void k_attn(
        const float* __restrict__ Q, const float* __restrict__ K,
        const float* __restrict__ V, const int* __restrict__ Mtop,
        float* __restrict__ out) {
    int blk = blockIdx.x; // bh*UU + u
    int u = blk % UU;
    int bh = blk / UU;
    int h = bh % HH, b = bh / HH;
    int qi = Mtop[bh * UU + u];
    int t = threadIdx.x;

    __shared__ float scores[LL];
    __shared__ float red[256];

    // Q row (pre-scaled) into registers: 16 float4s
    const float4* qp = (const float4*)(Q + qkv_idx(b, qi, h, 0));
    float4 qreg[16];
#pragma unroll
    for (int i = 0; i < 16; ++i) {
        float4 v = qp[i];
        v.x *= 0.125f; v.y *= 0.125f; v.z *= 0.125f; v.w *= 0.125f;
        qreg[i] = v;
    }

    // scores = (Q*scale) . K_k
    float lmax = -INFINITY;
    for (int k = t; k < LL; k += 256) {
        const float4* kr = (const float4*)(K + qkv_idx(b, k, h, 0));
        float dot = 0.f;
#pragma unroll
        for (int i = 0; i < 16; ++i) {
            float4 kk = kr[i];
            dot = fmaf(qreg[i].x, kk.x, dot);
            dot = fmaf(qreg[i].y, kk.y, dot);
            dot = fmaf(qreg[i].z, kk.z, dot);
            dot = fmaf(qreg[i].w, kk.w, dot);
        }
        scores[k] = dot;
        lmax = fmaxf(lmax, dot);
    }

    // block max
    red[t] = lmax;
    __syncthreads();
    for (int off = 128; off >= 1; off >>= 1) {
        if (t < off) red[t] = fmaxf(red[t], red[t + off]);
        __syncthreads();
    }
    float smax = red[0];
    __syncthreads();

    // exp + block sum
    float lsum = 0.f;
    for (int k = t; k < LL; k += 256) {
        float e = __expf(scores[k] - smax);
        scores[k] = e;
        lsum += e;
    }
    red[t] = lsum;
    __syncthreads();
    for (int off = 128; off >= 1; off >>= 1) {
        if (t < off) red[t] += red[t + off];
        __syncthreads();
    }
    float denom = red[0];
    __syncthreads(); // protect red before reuse

    // update[d] = sum_k scores[k] * V[k,d]   (lanes = d -> coalesced V reads)
    int d = t & 63, g = t >> 6;
    const float4* sc4 = (const float4*)scores;
    float acc = 0.f;
    for (int kb = g; kb < LL / 4; kb += 4) {
        float4 s4 = sc4[kb];
        int k0 = kb * 4;
        acc = fmaf(s4.x, V[qkv_idx(b, k0 + 0, h, d)], acc);
        acc = fmaf(s4.y, V[qkv_idx(b, k0 + 1, h, d)], acc);
        acc = fmaf(s4.z, V[qkv_idx(b, k0 + 2, h, d)], acc);
        acc = fmaf(s4.w, V[qkv_idx(b, k0 + 3, h, d)], acc);
    }
    red[t] = acc;
    __syncthreads();
    if (g == 0) {
        float s = red[d] + red[64 + d] + red[128 + d] + red[192 + d];
        out[qkv_idx(b, qi, h, d)] = s / denom;
    }
}

extern "C" void kernel_launch(void* const* d_in, const int* in_sizes, int n_in,
                              void* d_out, int out_size, void* d_ws, size_t ws_size,
                              hipStream_t stream) {
    const float* Q = (const float*)d_in[0];
    const float* K = (const float*)d_in[1];
    const float* V = (const float*)d_in[2];
    const int* idx = (const int*)d_in[3];
    float* out = (float*)d_out;

    char* ws = (char*)d_ws;
    float* M = (float*)ws;                                  // BB*HH*LL floats = 256 KB
    int* Mtop = (int*)(ws + (size_t)BB * HH * LL * 4);      // 720 ints
    float* tsum = (float*)(ws + (size_t)BB * HH * LL * 4 + 4096); // BB*HH*NTILES*DD floats

    // 1) sparsity metric M
    k_computeM<<<BB * HH * LL / 4, 256, 0, stream>>>(Q, K, idx, M);
    // 2) top-45 query indices per (b,h)
    k_topk<<<BB * HH, 256, 0, stream>>>(M, Mtop);
    // 3-5) cumsum(V) over L -> out
    k_tilesum<<<BB * HH * NTILES, 256, 0, stream>>>(V, tsum);
    k_scantiles<<<BB * HH, 64, 0, stream>>>(tsum);
    k_cumsum<<<BB * HH * NTILES, 256, 0, stream>>>(V, tsum, out);
    // 6) attention rows for selected queries, scattered over the cumsum rows
    k_attn<<<BB * HH * UU, 256, 0, stream>>>(Q, K, V, Mtop, out);
}

// Round 2
// 308.709 us; speedup vs baseline: 1.5980x; 1.5980x over previous
//
#include <hip/hip_runtime.h>
#include <math.h>

#define BB 2
#define LL 4096
#define HH 8
#define DD 64
#define UU 45
#define TILE 128
#define NTILES (LL / TILE) // 32

// split-K attention config
#define NC 64              // key chunks
#define CK (LL / NC)       // 64 keys per chunk
#define KSTR 68            // padded LDS row stride (floats) for K/V/Q tiles
#define SSTR 68            // padded LDS row stride for scores (CK=64 + 4)

__device__ __forceinline__ int qkv_idx(int b, int l, int h, int d) {
    return ((b * LL + l) * HH + h) * DD + d;
}

// ---------------- Kernel 1: sparsity metric M[b,h,q] ---------------------------
// One wave per query. 16 lanes cooperate per sampled K row (4 rows per load
// instruction -> contiguous 256B segments, ~4x fewer cache-line transactions
// than one-lane-per-row). Q held lane=d, broadcast via shuffles.
__global__ __launch_bounds__(256) void k_computeM(
        const float* __restrict__ Q, const float* __restrict__ K,
        const int* __restrict__ idx, float* __restrict__ M) {
    int w = (blockIdx.x * blockDim.x + threadIdx.x) >> 6; // global wave id
    int lane = threadIdx.x & 63;
    int q = w % LL;
    int bh = w / LL;            // b*HH + h
    int h = bh % HH, b = bh / HH;

    const float* Kbh = K + (size_t)(b * LL * HH + h) * DD;
    const size_t rowStride = (size_t)HH * DD; // 512 floats between key rows

    float qv = Q[qkv_idx(b, q, h, lane)];     // lane = d
    int myks = idx[q * UU + (lane < UU ? lane : 0)];

    int r = lane >> 4;    // which of 4 rows this lane helps load
    int c16 = lane & 15;  // position within 16-lane row group

    float q0 = __shfl(qv, c16 * 4 + 0, 64);
    float q1 = __shfl(qv, c16 * 4 + 1, 64);
    float q2 = __shfl(qv, c16 * 4 + 2, 64);
    float q3 = __shfl(qv, c16 * 4 + 3, 64);

    float mval = -INFINITY, sval = 0.f;
#pragma unroll
    for (int g = 0; g < 12; ++g) {           // 12 groups x 4 rows = 48 >= 45
        int s = g * 4 + r;
        int ks = __shfl(myks, s, 64);        // s <= 47 < 64; invalid s -> safe row
        const float4* kp = (const float4*)(Kbh + (size_t)ks * rowStride);
        float4 kk = kp[c16];
        float part = fmaf(kk.x, q0, fmaf(kk.y, q1, fmaf(kk.z, q2, kk.w * q3)));
        part += __shfl_xor(part, 8, 64);
        part += __shfl_xor(part, 4, 64);
        part += __shfl_xor(part, 2, 64);
        part += __shfl_xor(part, 1, 64);
        if (s < UU) { mval = fmaxf(mval, part); sval += part; }
    }
    // combine the 4 row groups (lanes differing in bits 4,5)
    mval = fmaxf(mval, __shfl_xor(mval, 16, 64));
    sval += __shfl_xor(sval, 16, 64);
    mval = fmaxf(mval, __shfl_xor(mval, 32, 64));
    sval += __shfl_xor(sval, 32, 64);
    if (lane == 0) M[bh * LL + q] = mval - sval * (1.0f / LL);
}

// ---------------- Kernel 2: top-45 indices per (b,h), lowest-index tie-break ----
__global__ __launch_bounds__(256) void k_topk(
        const float* __restrict__ M, int* __restrict__ Mtop) {
    int bh = blockIdx.x;
    __shared__ float vals[LL];
    __shared__ float rv[256];
    __shared__ int ri[256];
    int t = threadIdx.x;
    for (int i = t; i < LL; i += 256) vals[i] = M[bh * LL + i];
    __syncthreads();

    for (int iter = 0; iter < UU; ++iter) {
        float best = -INFINITY;
        int bi = LL;
        for (int i = t; i < LL; i += 256) {
            float v = vals[i];
            if (v > best || (v == best && i < bi)) { best = v; bi = i; }
        }
        rv[t] = best; ri[t] = bi;
        __syncthreads();
        for (int off = 128; off >= 1; off >>= 1) {
            if (t < off) {
                float v2 = rv[t + off]; int i2 = ri[t + off];
                if (v2 > rv[t] || (v2 == rv[t] && i2 < ri[t])) { rv[t] = v2; ri[t] = i2; }
            }
            __syncthreads();
        }
        int sel = ri[0];
        if (t == 0) {
            Mtop[bh * UU + iter] = sel;
            vals[sel] = -INFINITY;
        }
        __syncthreads();
    }
}

// ---------------- Kernel 3: per-tile sums of V over l (for cumsum) -------------
__global__ __launch_bounds__(256) void k_tilesum(
        const float* __restrict__ V, float* __restrict__ tsum) {
    int blk = blockIdx.x; // ((b*HH+h)*NTILES + tile)
    int tile = blk % NTILES;
    int bh = blk / NTILES;
    int h = bh % HH, b = bh / HH;
    int d = threadIdx.x & 63, g = threadIdx.x >> 6; // g in 0..3
    const int CH = TILE / 4;                        // 32
    int l0 = tile * TILE + g * CH;
    float acc = 0.f;
    for (int i = 0; i < CH; ++i) acc += V[qkv_idx(b, l0 + i, h, d)];
    __shared__ float red[4][DD];
    red[g][d] = acc;
    __syncthreads();
    if (g == 0) tsum[blk * DD + d] = red[0][d] + red[1][d] + red[2][d] + red[3][d];
}

// ---------------- Kernel 4: exclusive scan of tile sums (32 tiles, serial) -----
__global__ void k_scantiles(float* __restrict__ tsum) {
    int bh = blockIdx.x;
    int d = threadIdx.x; // 64 threads
    float off = 0.f;
    for (int t = 0; t < NTILES; ++t) {
        int i = (bh * NTILES + t) * DD + d;
        float v = tsum[i];
        tsum[i] = off;
        off += v;
    }
}

// ---------------- Kernel 5: write cumsum(V) to out -----------------------------
__global__ __launch_bounds__(256) void k_cumsum(
        const float* __restrict__ V, const float* __restrict__ tsum,
        float* __restrict__ out) {
    int blk = blockIdx.x;
    int tile = blk % NTILES;
    int bh = blk / NTILES;
    int h = bh % HH, b = bh / HH;
    int d = threadIdx.x & 63, g = threadIdx.x >> 6;
    const int CH = TILE / 4;
    int l0 = tile * TILE + g * CH;

    __shared__ float red[4][DD];
    float acc = 0.f;
    for (int i = 0; i < CH; ++i) acc += V[qkv_idx(b, l0 + i, h, d)];
    red[g][d] = acc;
    __syncthreads();

    float off = tsum[blk * DD + d];
    for (int gg = 0; gg < g; ++gg) off += red[gg][d];

    float run = off;
    for (int i = 0; i < CH; ++i) {
        run += V[qkv_idx(b, l0 + i, h, d)];
        out[qkv_idx(b, l0 + i, h, d)] = run;
    }
}

// ---------------- Kernel 6a: split-K flash attention partials ------------------
// Block = (b,h, key chunk of CK=64). Stages 45 Q rows + K chunk + V chunk in
// LDS (padded stride 68 -> worst 2-way bank aliasing = free). Register-blocked
// 3u x 4k score GEMM, chunk-local softmax (m,l), PV GEMM, partial outputs.
__global__ __launch_bounds__(256) void k_attn_partial(
        const float* __restrict__ Q, const float* __restrict__ K,
        const float* __restrict__ V, const int* __restrict__ Mtop,
        float* __restrict__ mPart, float* __restrict__ lPart,
        float* __restrict__ Op) {
    int blk = blockIdx.x;      // bh * NC + c
    int c = blk % NC;
    int bh = blk / NC;
    int h = bh % HH, b = bh / HH;
    int k0 = c * CK;
    int t = threadIdx.x;

    __shared__ float Qs[48 * KSTR];   // 13056 B (rows 45..47 zeroed)
    __shared__ float Ks[CK * KSTR];   // 17408 B (reused for V in PV phase)
    __shared__ float Ss[UU * SSTR];   // 12240 B

    const size_t rowStride = (size_t)HH * DD; // 512 floats
    const float* Qbh = Q + (size_t)(b * LL * HH + h) * DD;
    const float* Kbh = K + (size_t)(b * LL * HH + h) * DD;
    const float* Vbh = V + (size_t)(b * LL * HH + h) * DD;

    // stage Q rows (pre-scaled by 1/sqrt(D)=0.125), zero-pad rows 45..47
    for (int p = t; p < 48 * DD; p += 256) {
        int u = p >> 6, d = p & 63;
        float v = 0.f;
        if (u < UU) {
            int qi = Mtop[bh * UU + u];
            v = Qbh[(size_t)qi * rowStride + d] * 0.125f;
        }
        Qs[u * KSTR + d] = v;
    }
    // stage K chunk (coalesced float4)
    for (int p = t; p < CK * 16; p += 256) {
        int row = p >> 4, i = p & 15;
        *(float4*)&Ks[row * KSTR + i * 4] =
            *(const float4*)&Kbh[(size_t)(k0 + row) * rowStride + i * 4];
    }
    __syncthreads();

    // --- scores GEMM: thread tile 3u x 4k ---
    int kq = t & 15, uq = t >> 4;
    int u0 = uq * 3;
    float acc[3][4];
#pragma unroll
    for (int i = 0; i < 3; ++i)
#pragma unroll
        for (int j = 0; j < 4; ++j) acc[i][j] = 0.f;

#pragma unroll 4
    for (int dd = 0; dd < 16; ++dd) {
        float4 qf[3];
#pragma unroll
        for (int i = 0; i < 3; ++i)
            qf[i] = *(const float4*)&Qs[(u0 + i) * KSTR + dd * 4];
        float4 kf[4];
#pragma unroll
        for (int j = 0; j < 4; ++j)
            kf[j] = *(const float4*)&Ks[(kq + 16 * j) * KSTR + dd * 4];
#pragma unroll
        for (int i = 0; i < 3; ++i)
#pragma unroll
            for (int j = 0; j < 4; ++j) {
                acc[i][j] = fmaf(qf[i].x, kf[j].x, acc[i][j]);
                acc[i][j] = fmaf(qf[i].y, kf[j].y, acc[i][j]);
                acc[i][j] = fmaf(qf[i].z, kf[j].z, acc[i][j]);
                acc[i][j] = fmaf(qf[i].w, kf[j].w, acc[i][j]);
            }
    }
#pragma unroll
    for (int i = 0; i < 3; ++i) {
        int u = u0 + i;
        if (u < UU)
#pragma unroll
            for (int j = 0; j < 4; ++j) Ss[u * SSTR + kq + 16 * j] = acc[i][j];
    }
    __syncthreads();

    // stage V chunk into the K buffer (no one reads Ks until next barrier)
    for (int p = t; p < CK * 16; p += 256) {
        int row = p >> 4, i = p & 15;
        *(float4*)&Ks[row * KSTR + i * 4] =
            *(const float4*)&Vbh[(size_t)(k0 + row) * rowStride + i * 4];
    }

    // --- chunk-local softmax: 4 threads per u ---
    if (t < UU * 4) {
        int u = t >> 2, qq = t & 3;
        float mloc = -INFINITY;
        for (int j = 0; j < CK / 4; ++j)
            mloc = fmaxf(mloc, Ss[u * SSTR + qq + 4 * j]);
        mloc = fmaxf(mloc, __shfl_xor(mloc, 1, 64));
        mloc = fmaxf(mloc, __shfl_xor(mloc, 2, 64));
        float lloc = 0.f;
        for (int j = 0; j < CK / 4; ++j) {
            int kk = qq + 4 * j;
            float e = __expf(Ss[u * SSTR + kk] - mloc);
            Ss[u * SSTR + kk] = e;
            lloc += e;
        }
        lloc += __shfl_xor(lloc, 1, 64);
        lloc += __shfl_xor(lloc, 2, 64);
        if (qq == 0) {
            mPart[(bh * NC + c) * UU + u] = mloc;
            lPart[(bh * NC + c) * UU + u] = lloc;
        }
    }
    __syncthreads();

    // --- PV GEMM: thread tile 3u x 4d ---
    int dq = t & 15;
    int d0 = dq * 4;
    if (u0 < UU) { // uq==15 idle
        float4 o[3];
#pragma unroll
        for (int i = 0; i < 3; ++i) o[i] = make_float4(0.f, 0.f, 0.f, 0.f);
#pragma unroll 4
        for (int kc = 0; kc < CK / 4; ++kc) {
            float4 vk[4];
#pragma unroll
            for (int jj = 0; jj < 4; ++jj)
                vk[jj] = *(const float4*)&Ks[(4 * kc + jj) * KSTR + d0];
#pragma unroll
            for (int i = 0; i < 3; ++i) {
                float4 pf = *(const float4*)&Ss[(u0 + i) * SSTR + 4 * kc];
                o[i].x = fmaf(pf.x, vk[0].x, o[i].x);
                o[i].y = fmaf(pf.x, vk[0].y, o[i].y);
                o[i].z = fmaf(pf.x, vk[0].z, o[i].z);
                o[i].w = fmaf(pf.x, vk[0].w, o[i].w);
                o[i].x = fmaf(pf.y, vk[1].x, o[i].x);
                o[i].y = fmaf(pf.y, vk[1].y, o[i].y);
                o[i].z = fmaf(pf.y, vk[1].z, o[i].z);
                o[i].w = fmaf(pf.y, vk[1].w, o[i].w);
                o[i].x = fmaf(pf.z, vk[2].x, o[i].x);
                o[i].y = fmaf(pf.z, vk[2].y, o[i].y);
                o[i].z = fmaf(pf.z, vk[2].z, o[i].z);
                o[i].w = fmaf(pf.z, vk[2].w, o[i].w);
                o[i].x = fmaf(pf.w, vk[3].x, o[i].x);
                o[i].y = fmaf(pf.w, vk[3].y, o[i].y);
                o[i].z = fmaf(pf.w, vk[3].z, o[i].z);
                o[i].w = fmaf(pf.w, vk[3].w, o[i].w);
            }
        }
#pragma unroll
        for (int i = 0; i < 3; ++i) {
            int u = u0 + i;
            *(float4*)&Op[((size_t)(bh * NC + c) * UU + u) * DD + d0] = o[i];
        }
    }
}

// ---------------- Kernel 6b: flash combine across chunks, scatter --------------
__global__ void k_attn_combine(
        const int* __restrict__ Mtop, const float* __restrict__ mPart,
        const float* __restrict__ lPart, const float* __restrict__ Op,
        float* __restrict__ out) {
    int blk = blockIdx.x; // bh*UU + u
    int u = blk % UU;
    int bh = blk / UU;
    int h = bh % HH, b = bh / HH;
    int d = threadIdx.x;  // 64
    float gm = -INFINITY;
    for (int c = 0; c < NC; ++c)
        gm = fmaxf(gm, mPart[(bh * NC + c) * UU + u]);
    float denom = 0.f, acc = 0.f;
    for (int c = 0; c < NC; ++c) {
        int pi = (bh * NC + c) * UU + u;
        float w = __expf(mPart[pi] - gm);
        denom = fmaf(lPart[pi], w, denom);
        acc = fmaf(w, Op[(size_t)pi * DD + d], acc);
    }
    int qi = Mtop[bh * UU + u];
    out[qkv_idx(b, qi, h, d)] = acc / denom;
}

// ---------------- Fallback: monolithic per-(bh,u) attention --------------------
__global__ __launch_bounds__(256) void k_attn_mono(
        const float* __restrict__ Q, const float* __restrict__ K,
        const float* __restrict__ V, const int* __restrict__ Mtop,
        float* __restrict__ out) {
    int blk = blockIdx.x; // bh*UU + u
    int u = blk % UU;
    int bh = blk / UU;
    int h = bh % HH, b = bh / HH;
    int qi = Mtop[bh * UU + u];
    int t = threadIdx.x;

    __shared__ float scores[LL];
    __shared__ float red[256];

    const float4* qp = (const float4*)(Q + qkv_idx(b, qi, h, 0));
    float4 qreg[16];
#pragma unroll
    for (int i = 0; i < 16; ++i) {
        float4 v = qp[i];
        v.x *= 0.125f; v.y *= 0.125f; v.z *= 0.125f; v.w *= 0.125f;
        qreg[i] = v;
    }

    float lmax = -INFINITY;
    for (int k = t; k < LL; k += 256) {
        const float4* kr = (const float4*)(K + qkv_idx(b, k, h, 0));
        float dot = 0.f;
#pragma unroll
        for (int i = 0; i < 16; ++i) {
            float4 kk = kr[i];
            dot = fmaf(qreg[i].x, kk.x, dot);
            dot = fmaf(qreg[i].y, kk.y, dot);
            dot = fmaf(qreg[i].z, kk.z, dot);
            dot = fmaf(qreg[i].w, kk.w, dot);
        }
        scores[k] = dot;
        lmax = fmaxf(lmax, dot);
    }
    red[t] = lmax;
    __syncthreads();
    for (int off = 128; off >= 1; off >>= 1) {
        if (t < off) red[t] = fmaxf(red[t], red[t + off]);
        __syncthreads();
    }
    float smax = red[0];
    __syncthreads();

    float lsum = 0.f;
    for (int k = t; k < LL; k += 256) {
        float e = __expf(scores[k] - smax);
        scores[k] = e;
        lsum += e;
    }
    red[t] = lsum;
    __syncthreads();
    for (int off = 128; off >= 1; off >>= 1) {
        if (t < off) red[t] += red[t + off];
        __syncthreads();
    }
    float denom = red[0];
    __syncthreads();

    int d = t & 63, g = t >> 6;
    const float4* sc4 = (const float4*)scores;
    float acc = 0.f;
    for (int kb = g; kb < LL / 4; kb += 4) {
        float4 s4 = sc4[kb];
        int kk0 = kb * 4;
        acc = fmaf(s4.x, V[qkv_idx(b, kk0 + 0, h, d)], acc);
        acc = fmaf(s4.y, V[qkv_idx(b, kk0 + 1, h, d)], acc);
        acc = fmaf(s4.z, V[qkv_idx(b, kk0 + 2, h, d)], acc);
        acc = fmaf(s4.w, V[qkv_idx(b, kk0 + 3, h, d)], acc);
    }
    red[t] = acc;
    __syncthreads();
    if (g == 0) {
        float s = red[d] + red[64 + d] + red[128 + d] + red[192 + d];
        out[qkv_idx(b, qi, h, d)] = s / denom;
    }
}

extern "C" void kernel_launch(void* const* d_in, const int* in_sizes, int n_in,
                              void* d_out, int out_size, void* d_ws, size_t ws_size,
                              hipStream_t stream) {
    const float* Q = (const float*)d_in[0];
    const float* K = (const float*)d_in[1];
    const float* V = (const float*)d_in[2];
    const int* idx = (const int*)d_in[3];
    float* out = (float*)d_out;

    float* ws = (float*)d_ws;

    // workspace layout (floats)
    const size_t M_off = 0;                           // 65536
    const size_t tsum_off = 65536;                    // 32768
    const size_t mP_off = 98304;                      // 16*64*45 = 46080
    const size_t lP_off = 144384;                     // 46080
    const size_t top_off = 190464;                    // 720 ints (reserve 1024)
    const size_t Op_off = 191488;                     // 16*64*45*64 = 2949120
    const size_t need = (Op_off + (size_t)BB * HH * NC * UU * DD) * 4;

    float* M = ws + M_off;
    float* tsum = ws + tsum_off;

    if (ws_size >= need) {
        float* mPart = ws + mP_off;
        float* lPart = ws + lP_off;
        int* Mtop = (int*)(ws + top_off);
        float* Op = ws + Op_off;

        k_computeM<<<BB * HH * LL / 4, 256, 0, stream>>>(Q, K, idx, M);
        k_topk<<<BB * HH, 256, 0, stream>>>(M, Mtop);
        k_attn_partial<<<BB * HH * NC, 256, 0, stream>>>(Q, K, V, Mtop,
                                                         mPart, lPart, Op);
        k_tilesum<<<BB * HH * NTILES, 256, 0, stream>>>(V, tsum);
        k_scantiles<<<BB * HH, 64, 0, stream>>>(tsum);
        k_cumsum<<<BB * HH * NTILES, 256, 0, stream>>>(V, tsum, out);
        k_attn_combine<<<BB * HH * UU, 64, 0, stream>>>(Mtop, mPart, lPart,
                                                        Op, out);
    } else {
        // compact fallback layout
        int* Mtop = (int*)(ws + 65536);
        float* tsum2 = ws + 65536 + 1024;
        k_computeM<<<BB * HH * LL / 4, 256, 0, stream>>>(Q, K, idx, M);
        k_topk<<<BB * HH, 256, 0, stream>>>(M, Mtop);
        k_tilesum<<<BB * HH * NTILES, 256, 0, stream>>>(V, tsum2);
        k_scantiles<<<BB * HH, 64, 0, stream>>>(tsum2);
        k_cumsum<<<BB * HH * NTILES, 256, 0, stream>>>(V, tsum2, out);
        k_attn_mono<<<BB * HH * UU, 256, 0, stream>>>(Q, K, V, Mtop, out);
    }
}

// Round 3
// 207.532 us; speedup vs baseline: 2.3771x; 1.4875x over previous
//
#include <hip/hip_runtime.h>
#include <math.h>

#define BB 2
#define LL 4096
#define HH 8
#define DD 64
#define UU 45
#define TILE 128
#define NTILES (LL / TILE) // 32

// split-K attention config
#define NC 64              // key chunks
#define CK (LL / NC)       // 64 keys per chunk
#define KSTR 68            // padded LDS row stride (floats) for K/V/Q tiles
#define SSTR 68            // padded LDS row stride for scores (CK=64 + 4)

__device__ __forceinline__ int qkv_idx(int b, int l, int h, int d) {
    return ((b * LL + l) * HH + h) * DD + d;
}

// ---------------- Kernel 1: sparsity metric M[b,h,q] ---------------------------
// One wave per query. 16 lanes cooperate per sampled K row (4 rows per load
// instruction -> contiguous 256B segments). Q held lane=d, broadcast via shfl.
__global__ __launch_bounds__(256) void k_computeM(
        const float* __restrict__ Q, const float* __restrict__ K,
        const int* __restrict__ idx, float* __restrict__ M) {
    int w = (blockIdx.x * blockDim.x + threadIdx.x) >> 6; // global wave id
    int lane = threadIdx.x & 63;
    int q = w % LL;
    int bh = w / LL;            // b*HH + h
    int h = bh % HH, b = bh / HH;

    const float* Kbh = K + (size_t)(b * LL * HH + h) * DD;
    const size_t rowStride = (size_t)HH * DD; // 512 floats between key rows

    float qv = Q[qkv_idx(b, q, h, lane)];     // lane = d
    int myks = idx[q * UU + (lane < UU ? lane : 0)];

    int r = lane >> 4;    // which of 4 rows this lane helps load
    int c16 = lane & 15;  // position within 16-lane row group

    float q0 = __shfl(qv, c16 * 4 + 0, 64);
    float q1 = __shfl(qv, c16 * 4 + 1, 64);
    float q2 = __shfl(qv, c16 * 4 + 2, 64);
    float q3 = __shfl(qv, c16 * 4 + 3, 64);

    float mval = -INFINITY, sval = 0.f;
#pragma unroll
    for (int g = 0; g < 12; ++g) {           // 12 groups x 4 rows = 48 >= 45
        int s = g * 4 + r;
        int ks = __shfl(myks, s, 64);        // s <= 47 < 64; invalid s -> safe row
        const float4* kp = (const float4*)(Kbh + (size_t)ks * rowStride);
        float4 kk = kp[c16];
        float part = fmaf(kk.x, q0, fmaf(kk.y, q1, fmaf(kk.z, q2, kk.w * q3)));
        part += __shfl_xor(part, 8, 64);
        part += __shfl_xor(part, 4, 64);
        part += __shfl_xor(part, 2, 64);
        part += __shfl_xor(part, 1, 64);
        if (s < UU) { mval = fmaxf(mval, part); sval += part; }
    }
    // combine the 4 row groups (lanes differing in bits 4,5)
    mval = fmaxf(mval, __shfl_xor(mval, 16, 64));
    sval += __shfl_xor(sval, 16, 64);
    mval = fmaxf(mval, __shfl_xor(mval, 32, 64));
    sval += __shfl_xor(sval, 32, 64);
    if (lane == 0) M[bh * LL + q] = mval - sval * (1.0f / LL);
}

// ---------------- Kernel 2: top-45 via 4-pass radix select ---------------------
// One block of 1024 threads per (b,h). Monotonic key transform, 8-bit MSD
// radix passes locate the exact 45th-largest key; collection pass emits all
// strictly-greater indices plus the lowest-index ties (jax.lax.top_k order
// is irrelevant downstream -- only the SET of indices matters).
__global__ __launch_bounds__(1024) void k_topk(
        const float* __restrict__ M, int* __restrict__ Mtop) {
    int bh = blockIdx.x;
    int t = threadIdx.x;
    __shared__ unsigned keys[LL];      // 16 KB
    __shared__ unsigned hist[256];
    __shared__ unsigned scanbuf[256];
    __shared__ unsigned sPrefix, sMask, sK, sBin;
    __shared__ int outCount, eqCount;
    __shared__ int eqIdx[64];

    for (int i = t; i < LL; i += 1024) {
        unsigned u = __float_as_uint(M[bh * LL + i]);
        keys[i] = (u & 0x80000000u) ? ~u : (u | 0x80000000u);
    }
    if (t == 0) { sPrefix = 0u; sMask = 0u; sK = UU; outCount = 0; eqCount = 0; }
    __syncthreads();

    for (int pass = 0; pass < 4; ++pass) {
        int shift = 24 - pass * 8;
        if (t < 256) hist[t] = 0u;
        __syncthreads();
        unsigned prefix = sPrefix, mask = sMask;
        for (int i = t; i < LL; i += 1024) {
            unsigned k = keys[i];
            if ((k & mask) == prefix)
                atomicAdd(&hist[(k >> shift) & 0xFFu], 1u);
        }
        __syncthreads();
        if (t < 256) scanbuf[t] = hist[t];
        __syncthreads();
        // suffix-sum: scanbuf[b] = count of keys with digit >= b (in subset)
        for (int off = 1; off < 256; off <<= 1) {
            unsigned v = 0u;
            if (t < 256 && t + off < 256) v = scanbuf[t + off];
            __syncthreads();
            if (t < 256) scanbuf[t] += v;
            __syncthreads();
        }
        if (t < 256) {
            unsigned k = sK;
            unsigned geq = scanbuf[t];
            unsigned gt = (t < 255) ? scanbuf[t + 1] : 0u;
            if (gt < k && geq >= k) sBin = (unsigned)t;
        }
        __syncthreads();
        if (t == 0) {
            unsigned b = sBin;
            unsigned gt = (b < 255u) ? scanbuf[b + 1] : 0u;
            sK -= gt;
            sPrefix |= (b << shift);
            sMask |= (0xFFu << shift);
        }
        __syncthreads();
    }
    unsigned T = sPrefix;
    int kEq = (int)sK;

    for (int i = t; i < LL; i += 1024) {
        unsigned k = keys[i];
        if (k > T) {
            int slot = atomicAdd(&outCount, 1);
            Mtop[bh * UU + slot] = i;
        } else if (k == T) {
            int e = atomicAdd(&eqCount, 1);
            if (e < 64) eqIdx[e] = i;
        }
    }
    __syncthreads();

    if (t == 0) {
        int base = outCount; // == UU - kEq
        int ec = eqCount;
        if (ec <= 64) {
            for (int s = 0; s < UU; ++s) { // s < kEq, bounded loop for compiler
                if (s >= kEq) break;
                int bi = -1, bv = LL + 2;
                for (int j = 0; j < ec; ++j) {
                    int v = eqIdx[j];
                    if (v < bv) { bv = v; bi = j; }
                }
                Mtop[bh * UU + base + s] = bv;
                eqIdx[bi] = LL + 2;
            }
        } else {
            // paranoid fallback (massive duplicate values): serial lowest-index
            int got = 0;
            for (int i = 0; i < LL && got < kEq; ++i)
                if (keys[i] == T) { Mtop[bh * UU + base + got] = i; ++got; }
        }
    }
}

// ---------------- Kernel 3: per-tile sums of V over l (for cumsum) -------------
__global__ __launch_bounds__(256) void k_tilesum(
        const float* __restrict__ V, float* __restrict__ tsum) {
    int blk = blockIdx.x; // ((b*HH+h)*NTILES + tile)
    int tile = blk % NTILES;
    int bh = blk / NTILES;
    int h = bh % HH, b = bh / HH;
    int d = threadIdx.x & 63, g = threadIdx.x >> 6; // g in 0..3
    const int CH = TILE / 4;                        // 32
    int l0 = tile * TILE + g * CH;
    float acc = 0.f;
    for (int i = 0; i < CH; ++i) acc += V[qkv_idx(b, l0 + i, h, d)];
    __shared__ float red[4][DD];
    red[g][d] = acc;
    __syncthreads();
    if (g == 0) tsum[blk * DD + d] = red[0][d] + red[1][d] + red[2][d] + red[3][d];
}

// ---------------- Kernel 4: exclusive scan of tile sums (32 tiles, serial) -----
__global__ void k_scantiles(float* __restrict__ tsum) {
    int bh = blockIdx.x;
    int d = threadIdx.x; // 64 threads
    float off = 0.f;
    for (int t = 0; t < NTILES; ++t) {
        int i = (bh * NTILES + t) * DD + d;
        float v = tsum[i];
        tsum[i] = off;
        off += v;
    }
}

// ---------------- Kernel 5: write cumsum(V) to out -----------------------------
__global__ __launch_bounds__(256) void k_cumsum(
        const float* __restrict__ V, const float* __restrict__ tsum,
        float* __restrict__ out) {
    int blk = blockIdx.x;
    int tile = blk % NTILES;
    int bh = blk / NTILES;
    int h = bh % HH, b = bh / HH;
    int d = threadIdx.x & 63, g = threadIdx.x >> 6;
    const int CH = TILE / 4;
    int l0 = tile * TILE + g * CH;

    __shared__ float red[4][DD];
    float acc = 0.f;
    for (int i = 0; i < CH; ++i) acc += V[qkv_idx(b, l0 + i, h, d)];
    red[g][d] = acc;
    __syncthreads();

    float off = tsum[blk * DD + d];
    for (int gg = 0; gg < g; ++gg) off += red[gg][d];

    float run = off;
    for (int i = 0; i < CH; ++i) {
        run += V[qkv_idx(b, l0 + i, h, d)];
        out[qkv_idx(b, l0 + i, h, d)] = run;
    }
}

// ---------------- Kernel 6a: split-K flash attention partials ------------------
__global__ __launch_bounds__(256) void k_attn_partial(
        const float* __restrict__ Q, const float* __restrict__ K,
        const float* __restrict__ V, const int* __restrict__ Mtop,
        float* __restrict__ mPart, float* __restrict__ lPart,
        float* __restrict__ Op) {
    int blk = blockIdx.x;      // bh * NC + c
    int c = blk % NC;
    int bh = blk / NC;
    int h = bh % HH, b = bh / HH;
    int k0 = c * CK;
    int t = threadIdx.x;

    __shared__ float Qs[48 * KSTR];   // 13056 B (rows 45..47 zeroed)
    __shared__ float Ks[CK * KSTR];   // 17408 B (reused for V in PV phase)
    __shared__ float Ss[UU * SSTR];   // 12240 B

    const size_t rowStride = (size_t)HH * DD; // 512 floats
    const float* Qbh = Q + (size_t)(b * LL * HH + h) * DD;
    const float* Kbh = K + (size_t)(b * LL * HH + h) * DD;
    const float* Vbh = V + (size_t)(b * LL * HH + h) * DD;

    for (int p = t; p < 48 * DD; p += 256) {
        int u = p >> 6, d = p & 63;
        float v = 0.f;
        if (u < UU) {
            int qi = Mtop[bh * UU + u];
            v = Qbh[(size_t)qi * rowStride + d] * 0.125f;
        }
        Qs[u * KSTR + d] = v;
    }
    for (int p = t; p < CK * 16; p += 256) {
        int row = p >> 4, i = p & 15;
        *(float4*)&Ks[row * KSTR + i * 4] =
            *(const float4*)&Kbh[(size_t)(k0 + row) * rowStride + i * 4];
    }
    __syncthreads();

    // --- scores GEMM: thread tile 3u x 4k ---
    int kq = t & 15, uq = t >> 4;
    int u0 = uq * 3;
    float acc[3][4];
#pragma unroll
    for (int i = 0; i < 3; ++i)
#pragma unroll
        for (int j = 0; j < 4; ++j) acc[i][j] = 0.f;

#pragma unroll 4
    for (int dd = 0; dd < 16; ++dd) {
        float4 qf[3];
#pragma unroll
        for (int i = 0; i < 3; ++i)
            qf[i] = *(const float4*)&Qs[(u0 + i) * KSTR + dd * 4];
        float4 kf[4];
#pragma unroll
        for (int j = 0; j < 4; ++j)
            kf[j] = *(const float4*)&Ks[(kq + 16 * j) * KSTR + dd * 4];
#pragma unroll
        for (int i = 0; i < 3; ++i)
#pragma unroll
            for (int j = 0; j < 4; ++j) {
                acc[i][j] = fmaf(qf[i].x, kf[j].x, acc[i][j]);
                acc[i][j] = fmaf(qf[i].y, kf[j].y, acc[i][j]);
                acc[i][j] = fmaf(qf[i].z, kf[j].z, acc[i][j]);
                acc[i][j] = fmaf(qf[i].w, kf[j].w, acc[i][j]);
            }
    }
#pragma unroll
    for (int i = 0; i < 3; ++i) {
        int u = u0 + i;
        if (u < UU)
#pragma unroll
            for (int j = 0; j < 4; ++j) Ss[u * SSTR + kq + 16 * j] = acc[i][j];
    }
    __syncthreads();

    // stage V chunk into the K buffer (no one reads Ks until next barrier)
    for (int p = t; p < CK * 16; p += 256) {
        int row = p >> 4, i = p & 15;
        *(float4*)&Ks[row * KSTR + i * 4] =
            *(const float4*)&Vbh[(size_t)(k0 + row) * rowStride + i * 4];
    }

    // --- chunk-local softmax: 4 threads per u ---
    if (t < UU * 4) {
        int u = t >> 2, qq = t & 3;
        float mloc = -INFINITY;
        for (int j = 0; j < CK / 4; ++j)
            mloc = fmaxf(mloc, Ss[u * SSTR + qq + 4 * j]);
        mloc = fmaxf(mloc, __shfl_xor(mloc, 1, 64));
        mloc = fmaxf(mloc, __shfl_xor(mloc, 2, 64));
        float lloc = 0.f;
        for (int j = 0; j < CK / 4; ++j) {
            int kk = qq + 4 * j;
            float e = __expf(Ss[u * SSTR + kk] - mloc);
            Ss[u * SSTR + kk] = e;
            lloc += e;
        }
        lloc += __shfl_xor(lloc, 1, 64);
        lloc += __shfl_xor(lloc, 2, 64);
        if (qq == 0) {
            mPart[(bh * NC + c) * UU + u] = mloc;
            lPart[(bh * NC + c) * UU + u] = lloc;
        }
    }
    __syncthreads();

    // --- PV GEMM: thread tile 3u x 4d ---
    int dq = t & 15;
    int d0 = dq * 4;
    if (u0 < UU) { // uq==15 idle
        float4 o[3];
#pragma unroll
        for (int i = 0; i < 3; ++i) o[i] = make_float4(0.f, 0.f, 0.f, 0.f);
#pragma unroll 4
        for (int kc = 0; kc < CK / 4; ++kc) {
            float4 vk[4];
#pragma unroll
            for (int jj = 0; jj < 4; ++jj)
                vk[jj] = *(const float4*)&Ks[(4 * kc + jj) * KSTR + d0];
#pragma unroll
            for (int i = 0; i < 3; ++i) {
                float4 pf = *(const float4*)&Ss[(u0 + i) * SSTR + 4 * kc];
                o[i].x = fmaf(pf.x, vk[0].x, o[i].x);
                o[i].y = fmaf(pf.x, vk[0].y, o[i].y);
                o[i].z = fmaf(pf.x, vk[0].z, o[i].z);
                o[i].w = fmaf(pf.x, vk[0].w, o[i].w);
                o[i].x = fmaf(pf.y, vk[1].x, o[i].x);
                o[i].y = fmaf(pf.y, vk[1].y, o[i].y);
                o[i].z = fmaf(pf.y, vk[1].z, o[i].z);
                o[i].w = fmaf(pf.y, vk[1].w, o[i].w);
                o[i].x = fmaf(pf.z, vk[2].x, o[i].x);
                o[i].y = fmaf(pf.z, vk[2].y, o[i].y);
                o[i].z = fmaf(pf.z, vk[2].z, o[i].z);
                o[i].w = fmaf(pf.z, vk[2].w, o[i].w);
                o[i].x = fmaf(pf.w, vk[3].x, o[i].x);
                o[i].y = fmaf(pf.w, vk[3].y, o[i].y);
                o[i].z = fmaf(pf.w, vk[3].z, o[i].z);
                o[i].w = fmaf(pf.w, vk[3].w, o[i].w);
            }
        }
#pragma unroll
        for (int i = 0; i < 3; ++i) {
            int u = u0 + i;
            *(float4*)&Op[((size_t)(bh * NC + c) * UU + u) * DD + d0] = o[i];
        }
    }
}

// ---------------- Kernel 6b: flash combine across chunks, scatter --------------
__global__ void k_attn_combine(
        const int* __restrict__ Mtop, const float* __restrict__ mPart,
        const float* __restrict__ lPart, const float* __restrict__ Op,
        float* __restrict__ out) {
    int blk = blockIdx.x; // bh*UU + u
    int u = blk % UU;
    int bh = blk / UU;
    int h = bh % HH, b = bh / HH;
    int d = threadIdx.x;  // 64
    float gm = -INFINITY;
    for (int c = 0; c < NC; ++c)
        gm = fmaxf(gm, mPart[(bh * NC + c) * UU + u]);
    float denom = 0.f, acc = 0.f;
    for (int c = 0; c < NC; ++c) {
        int pi = (bh * NC + c) * UU + u;
        float w = __expf(mPart[pi] - gm);
        denom = fmaf(lPart[pi], w, denom);
        acc = fmaf(w, Op[(size_t)pi * DD + d], acc);
    }
    int qi = Mtop[bh * UU + u];
    out[qkv_idx(b, qi, h, d)] = acc / denom;
}

// ---------------- Fallback: monolithic per-(bh,u) attention --------------------
__global__ __launch_bounds__(256) void k_attn_mono(
        const float* __restrict__ Q, const float* __restrict__ K,
        const float* __restrict__ V, const int* __restrict__ Mtop,
        float* __restrict__ out) {
    int blk = blockIdx.x; // bh*UU + u
    int u = blk % UU;
    int bh = blk / UU;
    int h = bh % HH, b = bh / HH;
    int qi = Mtop[bh * UU + u];
    int t = threadIdx.x;

    __shared__ float scores[LL];
    __shared__ float red[256];

    const float4* qp = (const float4*)(Q + qkv_idx(b, qi, h, 0));
    float4 qreg[16];
#pragma unroll
    for (int i = 0; i < 16; ++i) {
        float4 v = qp[i];
        v.x *= 0.125f; v.y *= 0.125f; v.z *= 0.125f; v.w *= 0.125f;
        qreg[i] = v;
    }

    float lmax = -INFINITY;
    for (int k = t; k < LL; k += 256) {
        const float4* kr = (const float4*)(K + qkv_idx(b, k, h, 0));
        float dot = 0.f;
#pragma unroll
        for (int i = 0; i < 16; ++i) {
            float4 kk = kr[i];
            dot = fmaf(qreg[i].x, kk.x, dot);
            dot = fmaf(qreg[i].y, kk.y, dot);
            dot = fmaf(qreg[i].z, kk.z, dot);
            dot = fmaf(qreg[i].w, kk.w, dot);
        }
        scores[k] = dot;
        lmax = fmaxf(lmax, dot);
    }
    red[t] = lmax;
    __syncthreads();
    for (int off = 128; off >= 1; off >>= 1) {
        if (t < off) red[t] = fmaxf(red[t], red[t + off]);
        __syncthreads();
    }
    float smax = red[0];
    __syncthreads();

    float lsum = 0.f;
    for (int k = t; k < LL; k += 256) {
        float e = __expf(scores[k] - smax);
        scores[k] = e;
        lsum += e;
    }
    red[t] = lsum;
    __syncthreads();
    for (int off = 128; off >= 1; off >>= 1) {
        if (t < off) red[t] += red[t + off];
        __syncthreads();
    }
    float denom = red[0];
    __syncthreads();

    int d = t & 63, g = t >> 6;
    const float4* sc4 = (const float4*)scores;
    float acc = 0.f;
    for (int kb = g; kb < LL / 4; kb += 4) {
        float4 s4 = sc4[kb];
        int kk0 = kb * 4;
        acc = fmaf(s4.x, V[qkv_idx(b, kk0 + 0, h, d)], acc);
        acc = fmaf(s4.y, V[qkv_idx(b, kk0 + 1, h, d)], acc);
        acc = fmaf(s4.z, V[qkv_idx(b, kk0 + 2, h, d)], acc);
        acc = fmaf(s4.w, V[qkv_idx(b, kk0 + 3, h, d)], acc);
    }
    red[t] = acc;
    __syncthreads();
    if (g == 0) {
        float s = red[d] + red[64 + d] + red[128 + d] + red[192 + d];
        out[qkv_idx(b, qi, h, d)] = s / denom;
    }
}

extern "C" void kernel_launch(void* const* d_in, const int* in_sizes, int n_in,
                              void* d_out, int out_size, void* d_ws, size_t ws_size,
                              hipStream_t stream) {
    const float* Q = (const float*)d_in[0];
    const float* K = (const float*)d_in[1];
    const float* V = (const float*)d_in[2];
    const int* idx = (const int*)d_in[3];
    float* out = (float*)d_out;

    float* ws = (float*)d_ws;

    // workspace layout (floats)
    const size_t M_off = 0;                           // 65536
    const size_t tsum_off = 65536;                    // 32768
    const size_t mP_off = 98304;                      // 16*64*45 = 46080
    const size_t lP_off = 144384;                     // 46080
    const size_t top_off = 190464;                    // 720 ints (reserve 1024)
    const size_t Op_off = 191488;                     // 16*64*45*64 = 2949120
    const size_t need = (Op_off + (size_t)BB * HH * NC * UU * DD) * 4;

    float* M = ws + M_off;
    float* tsum = ws + tsum_off;

    if (ws_size >= need) {
        float* mPart = ws + mP_off;
        float* lPart = ws + lP_off;
        int* Mtop = (int*)(ws + top_off);
        float* Op = ws + Op_off;

        k_computeM<<<BB * HH * LL / 4, 256, 0, stream>>>(Q, K, idx, M);
        k_topk<<<BB * HH, 1024, 0, stream>>>(M, Mtop);
        k_attn_partial<<<BB * HH * NC, 256, 0, stream>>>(Q, K, V, Mtop,
                                                         mPart, lPart, Op);
        k_tilesum<<<BB * HH * NTILES, 256, 0, stream>>>(V, tsum);
        k_scantiles<<<BB * HH, 64, 0, stream>>>(tsum);
        k_cumsum<<<BB * HH * NTILES, 256, 0, stream>>>(V, tsum, out);
        k_attn_combine<<<BB * HH * UU, 64, 0, stream>>>(Mtop, mPart, lPart,
                                                        Op, out);
    } else {
        // compact fallback layout
        int* Mtop = (int*)(ws + 65536);
        float* tsum2 = ws + 65536 + 1024;
        k_computeM<<<BB * HH * LL / 4, 256, 0, stream>>>(Q, K, idx, M);
        k_topk<<<BB * HH, 1024, 0, stream>>>(M, Mtop);
        k_tilesum<<<BB * HH * NTILES, 256, 0, stream>>>(V, tsum2);
        k_scantiles<<<BB * HH, 64, 0, stream>>>(tsum2);
        k_cumsum<<<BB * HH * NTILES, 256, 0, stream>>>(V, tsum2, out);
        k_attn_mono<<<BB * HH * UU, 256, 0, stream>>>(Q, K, V, Mtop, out);
    }
}